// Round 9
// baseline (745.498 us; speedup 1.0000x reference)
//
#include <hip/hip_runtime.h>
#include <hip/hip_cooperative_groups.h>
#include <cstddef>
#include <cstdint>

namespace cg = cooperative_groups;

// Problem constants (from setup_inputs)
#define AA 512      // atoms
#define KK 256      // atom size
#define TT 16384    // signal length
#define BB 4        // batch
#define PP 128      // pad = K/2
#define LL 16385    // feature map length = T + 2P - K + 1
#define LPAD 16388  // fm row stride, padded to multiple of 4 for float4 stores
#define NC 65       // number of 256-wide chunks covering LL
#define NT2 33      // position tiles of 512 covering LL
#define SDN 260     // s_dn row stride (floats): 16B-aligned, bank offset 4/row

// 4-float-granularity LDS swizzle: bank rotation of 4 per 32-float block.
static __device__ __forceinline__ int swz4(int i){ return i + ((i >> 5) << 2); }

// ---------------- normalize dictionary atoms (+ zero output) ----------------
__global__ void k_norm(const float* __restrict__ d, float* __restrict__ dn,
                       float* __restrict__ out){
  int a = blockIdx.x, t = threadIdx.x;
  if (t < 128) out[a*128 + t] = 0.f;          // 512 blocks x 128 = BB*TT
  float v = d[a*KK + t];
  float s = v*v;
  #pragma unroll
  for (int off = 32; off > 0; off >>= 1) s += __shfl_down(s, off, 64);
  __shared__ float red[4];
  if ((t & 63) == 0) red[t >> 6] = s;
  __syncthreads();
  float tot = red[0] + red[1] + red[2] + red[3];
  dn[a*KK + t] = v / (sqrtf(tot) + 1e-8f);
}

// ---------------- 32-position ring-buffer correlation core ----------------
// acc[j] = sum_{k=0..255} dnrow[k] * s_r[swz4(32*tx + j + k)], j = 0..31.
// K-ascending fmaf chain per acc[j] (bitwise-stable across kernel versions).
__device__ __forceinline__ void corr32(const float* __restrict__ s_r,
                                       const float* __restrict__ dnrow,
                                       int tx, float acc[32]){
  const int base = tx*32;
  float r[32];
  #pragma unroll
  for (int q = 0; q < 8; ++q){
    float4 v = *(const float4*)(s_r + swz4(base + 4*q));
    r[4*q] = v.x; r[4*q+1] = v.y; r[4*q+2] = v.z; r[4*q+3] = v.w;
  }
  #pragma unroll
  for (int j = 0; j < 32; ++j) acc[j] = 0.f;
  for (int kb = 0; kb < 8; ++kb){            // k = kb*32 + kq*4 + kk
    #pragma unroll
    for (int kq = 0; kq < 8; ++kq){
      const int k0 = kb*32 + kq*4;
      const float4 w4 = *(const float4*)(dnrow + k0);                 // 4 weights
      const float4 f4 = *(const float4*)(s_r + swz4(base + k0 + 32)); // 4 refills
      #pragma unroll
      for (int kk = 0; kk < 4; ++kk){
        const float w = (&w4.x)[kk];
        const int km = (kq*4 + kk) & 31;     // k mod 32, compile-time
        #pragma unroll
        for (int j = 0; j < 32; ++j)
          acc[j] = fmaf(w, r[(km + j) & 31], acc[j]);
        r[km] = (&f4.x)[kk];                 // window slides by 1
      }
    }
  }
}

// ---------------- initial feature map + chunk maxima ----------------
// block: 256 thr = 16 tx (32 positions each) x 16 ty (atoms); tile 16x512
__global__ __launch_bounds__(256) void k_fm_init(const float* __restrict__ x,
                                                 const float* __restrict__ dn,
                                                 float* __restrict__ fm,
                                                 float* __restrict__ cmv,
                                                 int* __restrict__ cml){
  const int lt = blockIdx.x, at = blockIdx.y, b = blockIdx.z;
  const int l0 = lt*512, a0 = at*16;
  const int tid = threadIdx.x;
  const int tx = tid & 15, ty = tid >> 4;

  __shared__ __align__(16) float s_r[860];      // 768 swizzled floats
  __shared__ __align__(16) float s_dn[16*SDN];  // 16 atoms, stride 260

  for (int i = tid; i < 768; i += 256){
    int t = l0 + i - PP;                        // padded coords -> signal index
    s_r[swz4(i)] = (t >= 0 && t < TT) ? x[b*TT + t] : 0.f;
  }
  for (int i = tid; i < 16*KK; i += 256){
    int aa = i >> 8, k = i & 255;
    s_dn[aa*SDN + k] = dn[(size_t)(a0 + aa)*KK + k];
  }
  __syncthreads();

  float acc[32];
  corr32(s_r, &s_dn[ty*SDN], tx, acc);

  const int base = tx*32;
  const size_t rowoff = ((size_t)b*AA + a0 + ty)*LPAD + l0 + base;
  float best = -1e30f; int bestl = l0 + base;
  if (l0 + 512 <= LL){
    #pragma unroll
    for (int q = 0; q < 8; ++q){
      float4 v4; v4.x = acc[4*q]; v4.y = acc[4*q+1]; v4.z = acc[4*q+2]; v4.w = acc[4*q+3];
      *(float4*)(fm + rowoff + 4*q) = v4;
    }
    #pragma unroll
    for (int j = 0; j < 32; ++j)
      if (acc[j] > best){ best = acc[j]; bestl = l0 + base + j; }
  } else {
    #pragma unroll
    for (int j = 0; j < 32; ++j){
      int l = l0 + base + j;
      if (l < LL){
        fm[rowoff + j] = acc[j];
        if (acc[j] > best){ best = acc[j]; bestl = l; }
      }
    }
  }
  // thread's 32 positions sit in one 256-chunk: chunk = lt*2 + (tx>>3).
  #pragma unroll
  for (int m = 1; m < 8; m <<= 1){
    float ov = __shfl_xor(best, m, 64);
    int   ol = __shfl_xor(bestl, m, 64);
    if (ov > best || (ov == best && ol < bestl)){ best = ov; bestl = ol; }
  }
  int ch = lt*2 + (tx >> 3);
  if ((tx & 7) == 0 && ch < NC){
    size_t ci = ((size_t)b*AA + a0 + ty)*NC + ch;
    cmv[ci] = best; cml[ci] = bestl;
  }
}

// ---------------- cooperative loop: rowmax + 8x(select -> rec -> update) ----------------
// grid 128 = 32 a-slices x 4 batch; block 256 = 16 tx x 16 ty(atoms)
__global__ __launch_bounds__(256) void k_loop(const float* __restrict__ dn,
                                              float* __restrict__ fm,
                                              float* __restrict__ cmv, int* __restrict__ cml,
                                              float* __restrict__ amv, int* __restrict__ aml,
                                              float* __restrict__ out,
                                              const int* __restrict__ nit){
  cg::grid_group grid = cg::this_grid();
  const int as = blockIdx.x & 31;              // a-slice: atoms [as*16, as*16+16)
  const int b  = blockIdx.x >> 5;
  const int a0 = as*16;
  const int tid = threadIdx.x, tx = tid & 15, ty = tid >> 4;
  const int n = *nit;

  __shared__ __align__(16) float s_e[860];     // zero-extended dn[sel_atom]
  __shared__ __align__(16) float s_dn[16*SDN]; // this block's 16 atoms (persistent)
  __shared__ float sv[256]; __shared__ int sa[256]; __shared__ int sl[256];

  for (int i = tid; i < 16*KK; i += 256){
    int aa = i >> 8, k = i & 255;
    s_dn[aa*SDN + k] = dn[(size_t)(a0 + aa)*KK + k];
  }

  // phase 0: per-atom row maxima from chunk maxima
  {
    const size_t row = (size_t)b*AA + a0 + ty;
    float best = -1e30f; int bestl = 0;
    for (int c = tx; c < NC; c += 16){
      float v = cmv[row*NC + c]; int l = cml[row*NC + c];
      if (v > best || (v == best && l < bestl)){ best = v; bestl = l; }
    }
    #pragma unroll
    for (int m = 1; m < 16; m <<= 1){
      float ov = __shfl_xor(best, m, 64);
      int   ol = __shfl_xor(bestl, m, 64);
      if (ov > best || (ov == best && ol < bestl)){ best = ov; bestl = ol; }
    }
    if (tx == 0){ amv[b*AA + a0 + ty] = best; aml[b*AA + a0 + ty] = bestl; }
  }
  grid.sync();

  for (int it = 0; it < 8; ++it){
    if (it >= n) break;                        // uniform across grid
    // ---- select: argmax over this b's 512 per-atom maxima (redundant per block)
    {
      float best = amv[b*AA + tid]; int ba = tid, bl = aml[b*AA + tid];
      float v2 = amv[b*AA + tid + 256]; int l2 = aml[b*AA + tid + 256];
      if (v2 > best){ best = v2; ba = tid + 256; bl = l2; }  // strict > keeps low-index tie
      sv[tid] = best; sa[tid] = ba; sl[tid] = bl;
      __syncthreads();
      for (int s = 128; s > 0; s >>= 1){
        if (tid < s){
          float ov = sv[tid+s]; int oa = sa[tid+s], ol = sl[tid+s];
          bool take = ov > sv[tid] || (ov == sv[tid] && oa < sa[tid]);
          if (take){ sv[tid] = ov; sa[tid] = oa; sl[tid] = ol; }
        }
        __syncthreads();
      }
    }
    const float val = sv[0]; const int c = sa[0], pos = sl[0];
    // ---- reconstruction write (one block per b)
    if (as == 0){
      int t = pos + tid - PP;
      if (t >= 0 && t < TT) out[b*TT + t] += val * dn[(size_t)c*KK + tid];
    }
    const bool last = (it == 7) || (it + 1 >= n);
    if (!last){
      // stage zero-extended selected atom: e[i] = dn_c[i-256]
      for (int i = tid; i < 768; i += 256){
        int k = i - 256;
        s_e[swz4(i)] = (k >= 0 && k < KK) ? dn[(size_t)c*KK + k] : 0.f;
      }
    }
    grid.sync();   // SYNC-A: all sel reads of amv done; s_e staged (includes block barrier)

    if (!last){
      float acc[32];                           // acc[j] = G(a0+ty, c, 32*tx + j - 256)
      corr32(s_e, &s_dn[ty*SDN], tx, acc);

      const size_t rb = ((size_t)b*AA + a0 + ty)*LPAD;
      const int lb = pos - 256 + tx*32;
      #pragma unroll
      for (int j = 0; j < 32; ++j){
        int l = lb + j;
        if (l >= 0 && l < LL) fm[rb + l] -= val * acc[j];
      }
      __syncthreads();   // block's fm updates visible block-wide (rows owned per-block)

      // refresh touched chunks (<=3)
      int lo = pos - 255; if (lo < 0) lo = 0;
      int hi = pos + 255; if (hi > LL-1) hi = LL-1;
      const int c0 = lo >> 8, c1 = hi >> 8;
      for (int ch = c0; ch <= c1; ++ch){
        int lbase = ch*256 + tx*16;
        float best = -1e30f; int bestl = lbase;
        #pragma unroll
        for (int j = 0; j < 16; ++j){
          int l = lbase + j;
          if (l < LL){
            float v = fm[rb + l];
            if (v > best){ best = v; bestl = l; }
          }
        }
        #pragma unroll
        for (int m = 1; m < 16; m <<= 1){
          float ov = __shfl_xor(best, m, 64);
          int   ol = __shfl_xor(bestl, m, 64);
          if (ov > best || (ov == best && ol < bestl)){ best = ov; bestl = ol; }
        }
        if (tx == 0){
          size_t ci = ((size_t)b*AA + a0 + ty)*NC + ch;
          cmv[ci] = best; cml[ci] = bestl;
        }
      }
      __syncthreads();   // fresh cmv visible block-wide

      // recompute this block's 16 per-atom row maxima
      const size_t row = (size_t)b*AA + a0 + ty;
      float best = -1e30f; int bestl = 0;
      for (int cc = tx; cc < NC; cc += 16){
        float v = cmv[row*NC + cc]; int l = cml[row*NC + cc];
        if (v > best || (v == best && l < bestl)){ best = v; bestl = l; }
      }
      #pragma unroll
      for (int m = 1; m < 16; m <<= 1){
        float ov = __shfl_xor(best, m, 64);
        int   ol = __shfl_xor(bestl, m, 64);
        if (ov > best || (ov == best && ol < bestl)){ best = ov; bestl = ol; }
      }
      if (tx == 0){ amv[b*AA + a0 + ty] = best; aml[b*AA + a0 + ty] = bestl; }
    }
    grid.sync();   // SYNC-B: amv/fm/cmv updates visible grid-wide before next select
  }
}

extern "C" void kernel_launch(void* const* d_in, const int* in_sizes, int n_in,
                              void* d_out, int out_size, void* d_ws, size_t ws_size,
                              hipStream_t stream){
  const float* x  = (const float*)d_in[0];
  const float* d  = (const float*)d_in[1];
  const int*  nit = (const int*)d_in[2];
  float* out = (float*)d_out;

  // workspace carve (all fp32/int32)
  float* dn  = (float*)d_ws;                       // AA*KK
  float* fm  = dn  + (size_t)AA*KK;                // BB*AA*LPAD
  float* cmv = fm  + (size_t)BB*AA*LPAD;           // BB*AA*NC
  int*   cml = (int*)(cmv + (size_t)BB*AA*NC);     // BB*AA*NC
  float* amv = (float*)(cml + (size_t)BB*AA*NC);   // BB*AA
  int*   aml = (int*)(amv + (size_t)BB*AA);        // BB*AA
  size_t need = (size_t)((char*)(aml + (size_t)BB*AA) - (char*)d_ws);
  if (ws_size < need) return;  // visible failure instead of OOB corruption

  k_norm<<<AA, KK, 0, stream>>>(d, dn, out);
  k_fm_init<<<dim3(NT2, AA/16, BB), 256, 0, stream>>>(x, dn, fm, cmv, cml);

  void* args[] = {(void*)&dn, (void*)&fm, (void*)&cmv, (void*)&cml,
                  (void*)&amv, (void*)&aml, (void*)&out, (void*)&nit};
  hipLaunchCooperativeKernel((void*)k_loop, dim3(32*BB), dim3(256), args, 0, stream);
}

// Round 11
// 592.581 us; speedup vs baseline: 1.2581x; 1.2581x over previous
//
#include <hip/hip_runtime.h>
#include <cstddef>
#include <cstdint>

// Problem constants (from setup_inputs)
#define AA 512      // atoms
#define KK 256      // atom size
#define TT 16384    // signal length
#define BB 4        // batch
#define PP 128      // pad = K/2
#define LL 16385    // feature map length = T + 2P - K + 1
#define LPAD 16388  // fm row stride, padded to multiple of 4 for float4 stores
#define NC 65       // number of 256-wide chunks covering LL
#define NT2 33      // position tiles of 512 covering LL
#define SDN 260     // s_dn row stride (floats): 16B-aligned, bank offset 4/row
#define NBLK 128    // k_loop grid size (32 a-slices x 4 batch)

// 4-float-granularity LDS swizzle: bank rotation of 4 per 32-float block.
static __device__ __forceinline__ int swz4(int i){ return i + ((i >> 5) << 2); }

// All-to-all flag grid barrier (cg::grid.sync measured ~25-30us on this grid;
// this is the standard release/acquire flag pattern, ~1-3us expected).
// Each block release-stores its flag=g; threads 0..NBLK-1 acquire-poll one
// flag each; closing __syncthreads makes the block wait for all 128.
static __device__ __forceinline__ void gridbar(int* __restrict__ flags, int g){
  __syncthreads();                       // all block work done; orders s_e WAR too
  const int tid = threadIdx.x;
  if (tid == 0)
    __hip_atomic_store(&flags[blockIdx.x], g, __ATOMIC_RELEASE, __HIP_MEMORY_SCOPE_AGENT);
  if (tid < NBLK){
    while (__hip_atomic_load(&flags[tid], __ATOMIC_ACQUIRE, __HIP_MEMORY_SCOPE_AGENT) < g)
      __builtin_amdgcn_s_sleep(1);
  }
  __syncthreads();
}

// ---------------- normalize dictionary atoms (+ zero output, barrier flags) ----------------
__global__ void k_norm(const float* __restrict__ d, float* __restrict__ dn,
                       float* __restrict__ out, int* __restrict__ flags){
  int a = blockIdx.x, t = threadIdx.x;
  if (t < 128) out[a*128 + t] = 0.f;          // 512 blocks x 128 = BB*TT
  if (a == 0 && t < NBLK) flags[t] = 0;       // reset barrier state every call
  float v = d[a*KK + t];
  float s = v*v;
  #pragma unroll
  for (int off = 32; off > 0; off >>= 1) s += __shfl_down(s, off, 64);
  __shared__ float red[4];
  if ((t & 63) == 0) red[t >> 6] = s;
  __syncthreads();
  float tot = red[0] + red[1] + red[2] + red[3];
  dn[a*KK + t] = v / (sqrtf(tot) + 1e-8f);
}

// ---------------- 32-position ring-buffer correlation core ----------------
// acc[j] = sum_{k=0..255} dnrow[k] * s_r[swz4(32*tx + j + k)], j = 0..31.
// K-ascending fmaf chain per acc[j] (bitwise-stable across kernel versions).
__device__ __forceinline__ void corr32(const float* __restrict__ s_r,
                                       const float* __restrict__ dnrow,
                                       int tx, float acc[32]){
  const int base = tx*32;
  float r[32];
  #pragma unroll
  for (int q = 0; q < 8; ++q){
    float4 v = *(const float4*)(s_r + swz4(base + 4*q));
    r[4*q] = v.x; r[4*q+1] = v.y; r[4*q+2] = v.z; r[4*q+3] = v.w;
  }
  #pragma unroll
  for (int j = 0; j < 32; ++j) acc[j] = 0.f;
  for (int kb = 0; kb < 8; ++kb){            // k = kb*32 + kq*4 + kk
    #pragma unroll
    for (int kq = 0; kq < 8; ++kq){
      const int k0 = kb*32 + kq*4;
      const float4 w4 = *(const float4*)(dnrow + k0);                 // 4 weights
      const float4 f4 = *(const float4*)(s_r + swz4(base + k0 + 32)); // 4 refills
      #pragma unroll
      for (int kk = 0; kk < 4; ++kk){
        const float w = (&w4.x)[kk];
        const int km = (kq*4 + kk) & 31;     // k mod 32, compile-time
        #pragma unroll
        for (int j = 0; j < 32; ++j)
          acc[j] = fmaf(w, r[(km + j) & 31], acc[j]);
        r[km] = (&f4.x)[kk];                 // window slides by 1
      }
    }
  }
}

// ---------------- initial feature map + chunk maxima ----------------
// block: 256 thr = 16 tx (32 positions each) x 16 ty (atoms); tile 16x512
__global__ __launch_bounds__(256) void k_fm_init(const float* __restrict__ x,
                                                 const float* __restrict__ dn,
                                                 float* __restrict__ fm,
                                                 float* __restrict__ cmv,
                                                 int* __restrict__ cml){
  const int lt = blockIdx.x, at = blockIdx.y, b = blockIdx.z;
  const int l0 = lt*512, a0 = at*16;
  const int tid = threadIdx.x;
  const int tx = tid & 15, ty = tid >> 4;

  __shared__ __align__(16) float s_r[860];      // 768 swizzled floats
  __shared__ __align__(16) float s_dn[16*SDN];  // 16 atoms, stride 260

  for (int i = tid; i < 768; i += 256){
    int t = l0 + i - PP;                        // padded coords -> signal index
    s_r[swz4(i)] = (t >= 0 && t < TT) ? x[b*TT + t] : 0.f;
  }
  for (int i = tid; i < 16*KK; i += 256){
    int aa = i >> 8, k = i & 255;
    s_dn[aa*SDN + k] = dn[(size_t)(a0 + aa)*KK + k];
  }
  __syncthreads();

  float acc[32];
  corr32(s_r, &s_dn[ty*SDN], tx, acc);

  const int base = tx*32;
  const size_t rowoff = ((size_t)b*AA + a0 + ty)*LPAD + l0 + base;
  float best = -1e30f; int bestl = l0 + base;
  if (l0 + 512 <= LL){
    #pragma unroll
    for (int q = 0; q < 8; ++q){
      float4 v4; v4.x = acc[4*q]; v4.y = acc[4*q+1]; v4.z = acc[4*q+2]; v4.w = acc[4*q+3];
      *(float4*)(fm + rowoff + 4*q) = v4;
    }
    #pragma unroll
    for (int j = 0; j < 32; ++j)
      if (acc[j] > best){ best = acc[j]; bestl = l0 + base + j; }
  } else {
    #pragma unroll
    for (int j = 0; j < 32; ++j){
      int l = l0 + base + j;
      if (l < LL){
        fm[rowoff + j] = acc[j];
        if (acc[j] > best){ best = acc[j]; bestl = l; }
      }
    }
  }
  // thread's 32 positions sit in one 256-chunk: chunk = lt*2 + (tx>>3).
  #pragma unroll
  for (int m = 1; m < 8; m <<= 1){
    float ov = __shfl_xor(best, m, 64);
    int   ol = __shfl_xor(bestl, m, 64);
    if (ov > best || (ov == best && ol < bestl)){ best = ov; bestl = ol; }
  }
  int ch = lt*2 + (tx >> 3);
  if ((tx & 7) == 0 && ch < NC){
    size_t ci = ((size_t)b*AA + a0 + ty)*NC + ch;
    cmv[ci] = best; cml[ci] = bestl;
  }
}

// ---------------- persistent loop: rowmax + 8x(select -> rec -> update) ----------------
// grid 128 = 32 a-slices x 4 batch; block 256 = 16 tx x 16 ty(atoms).
// amv/aml double-buffered: select(it) reads buf[it&1], update(it) writes
// buf[(it+1)&1] -> only ONE grid barrier per iteration (update -> next select).
__global__ __launch_bounds__(256) void k_loop(const float* __restrict__ dn,
                                              float* __restrict__ fm,
                                              float* __restrict__ cmv, int* __restrict__ cml,
                                              float* __restrict__ amv, int* __restrict__ aml,
                                              float* __restrict__ out,
                                              const int* __restrict__ nit,
                                              int* __restrict__ flags){
  const int as = blockIdx.x & 31;              // a-slice: atoms [as*16, as*16+16)
  const int b  = blockIdx.x >> 5;
  const int a0 = as*16;
  const int tid = threadIdx.x, tx = tid & 15, ty = tid >> 4;
  const int n = *nit;
  int g = 0;

  __shared__ __align__(16) float s_e[860];     // zero-extended dn[sel_atom]
  __shared__ __align__(16) float s_dn[16*SDN]; // this block's 16 atoms (persistent)
  __shared__ float sv[256]; __shared__ int sa[256]; __shared__ int sl[256];

  for (int i = tid; i < 16*KK; i += 256){
    int aa = i >> 8, k = i & 255;
    s_dn[aa*SDN + k] = dn[(size_t)(a0 + aa)*KK + k];
  }

  // phase 0: per-atom row maxima from chunk maxima -> buffer 0
  {
    const size_t row = (size_t)b*AA + a0 + ty;
    float best = -1e30f; int bestl = 0;
    for (int c = tx; c < NC; c += 16){
      float v = cmv[row*NC + c]; int l = cml[row*NC + c];
      if (v > best || (v == best && l < bestl)){ best = v; bestl = l; }
    }
    #pragma unroll
    for (int m = 1; m < 16; m <<= 1){
      float ov = __shfl_xor(best, m, 64);
      int   ol = __shfl_xor(bestl, m, 64);
      if (ov > best || (ov == best && ol < bestl)){ best = ov; bestl = ol; }
    }
    if (tx == 0){ amv[b*AA + a0 + ty] = best; aml[b*AA + a0 + ty] = bestl; }
  }
  gridbar(flags, ++g);

  for (int it = 0; it < 8; ++it){
    if (it >= n) break;                        // uniform across grid
    const float* av  = amv + (size_t)(it & 1)*BB*AA;
    const int*   al  = aml + (size_t)(it & 1)*BB*AA;
    float*       avn = amv + (size_t)((it + 1) & 1)*BB*AA;
    int*         aln = aml + (size_t)((it + 1) & 1)*BB*AA;

    // ---- select: argmax over this b's 512 per-atom maxima (redundant per block)
    {
      float best = av[b*AA + tid]; int ba = tid, bl = al[b*AA + tid];
      float v2 = av[b*AA + tid + 256]; int l2 = al[b*AA + tid + 256];
      if (v2 > best){ best = v2; ba = tid + 256; bl = l2; }  // strict > keeps low-index tie
      sv[tid] = best; sa[tid] = ba; sl[tid] = bl;
      __syncthreads();
      for (int s = 128; s > 0; s >>= 1){
        if (tid < s){
          float ov = sv[tid+s]; int oa = sa[tid+s], ol = sl[tid+s];
          bool take = ov > sv[tid] || (ov == sv[tid] && oa < sa[tid]);
          if (take){ sv[tid] = ov; sa[tid] = oa; sl[tid] = ol; }
        }
        __syncthreads();
      }
    }
    const float val = sv[0]; const int c = sa[0], pos = sl[0];
    // ---- reconstruction write (one block per b)
    if (as == 0){
      int t = pos + tid - PP;
      if (t >= 0 && t < TT) out[b*TT + t] += val * dn[(size_t)c*KK + tid];
    }
    const bool last = (it == 7) || (it + 1 >= n);
    if (!last){
      // stage zero-extended selected atom: e[i] = dn_c[i-256]
      for (int i = tid; i < 768; i += 256){
        int k = i - 256;
        s_e[swz4(i)] = (k >= 0 && k < KK) ? dn[(size_t)c*KK + k] : 0.f;
      }
      __syncthreads();   // s_e staged before corr32 reads it

      float acc[32];                           // acc[j] = G(a0+ty, c, 32*tx + j - 256)
      corr32(s_e, &s_dn[ty*SDN], tx, acc);

      const size_t rb = ((size_t)b*AA + a0 + ty)*LPAD;
      const int lb = pos - 256 + tx*32;
      #pragma unroll
      for (int j = 0; j < 32; ++j){
        int l = lb + j;
        if (l >= 0 && l < LL) fm[rb + l] -= val * acc[j];
      }
      __syncthreads();   // block's fm updates visible block-wide (rows owned per-block)

      // refresh touched chunks (<=3)
      int lo = pos - 255; if (lo < 0) lo = 0;
      int hi = pos + 255; if (hi > LL-1) hi = LL-1;
      const int c0 = lo >> 8, c1 = hi >> 8;
      for (int ch = c0; ch <= c1; ++ch){
        int lbase = ch*256 + tx*16;
        float best = -1e30f; int bestl = lbase;
        #pragma unroll
        for (int j = 0; j < 16; ++j){
          int l = lbase + j;
          if (l < LL){
            float v = fm[rb + l];
            if (v > best){ best = v; bestl = l; }
          }
        }
        #pragma unroll
        for (int m = 1; m < 16; m <<= 1){
          float ov = __shfl_xor(best, m, 64);
          int   ol = __shfl_xor(bestl, m, 64);
          if (ov > best || (ov == best && ol < bestl)){ best = ov; bestl = ol; }
        }
        if (tx == 0){
          size_t ci = ((size_t)b*AA + a0 + ty)*NC + ch;
          cmv[ci] = best; cml[ci] = bestl;
        }
      }
      __syncthreads();   // fresh cmv visible block-wide

      // recompute this block's 16 per-atom row maxima -> NEXT buffer
      const size_t row = (size_t)b*AA + a0 + ty;
      float best = -1e30f; int bestl = 0;
      for (int cc = tx; cc < NC; cc += 16){
        float v = cmv[row*NC + cc]; int l = cml[row*NC + cc];
        if (v > best || (v == best && l < bestl)){ best = v; bestl = l; }
      }
      #pragma unroll
      for (int m = 1; m < 16; m <<= 1){
        float ov = __shfl_xor(best, m, 64);
        int   ol = __shfl_xor(bestl, m, 64);
        if (ov > best || (ov == best && ol < bestl)){ best = ov; bestl = ol; }
      }
      if (tx == 0){ avn[b*AA + a0 + ty] = best; aln[b*AA + a0 + ty] = bestl; }

      gridbar(flags, ++g);   // update writes visible grid-wide before next select
    }
  }
}

extern "C" void kernel_launch(void* const* d_in, const int* in_sizes, int n_in,
                              void* d_out, int out_size, void* d_ws, size_t ws_size,
                              hipStream_t stream){
  const float* x  = (const float*)d_in[0];
  const float* d  = (const float*)d_in[1];
  const int*  nit = (const int*)d_in[2];
  float* out = (float*)d_out;

  // workspace carve (all fp32/int32)
  float* dn  = (float*)d_ws;                       // AA*KK
  float* fm  = dn  + (size_t)AA*KK;                // BB*AA*LPAD
  float* cmv = fm  + (size_t)BB*AA*LPAD;           // BB*AA*NC
  int*   cml = (int*)(cmv + (size_t)BB*AA*NC);     // BB*AA*NC
  float* amv = (float*)(cml + (size_t)BB*AA*NC);   // 2*BB*AA (double-buffered)
  int*   aml = (int*)(amv + (size_t)2*BB*AA);      // 2*BB*AA
  int*   flags = aml + (size_t)2*BB*AA;            // NBLK barrier flags
  size_t need = (size_t)((char*)(flags + NBLK) - (char*)d_ws);
  if (ws_size < need) return;  // visible failure instead of OOB corruption

  k_norm<<<AA, KK, 0, stream>>>(d, dn, out, flags);
  k_fm_init<<<dim3(NT2, AA/16, BB), 256, 0, stream>>>(x, dn, fm, cmv, cml);

  void* args[] = {(void*)&dn, (void*)&fm, (void*)&cmv, (void*)&cml,
                  (void*)&amv, (void*)&aml, (void*)&out, (void*)&nit, (void*)&flags};
  hipLaunchCooperativeKernel((void*)k_loop, dim3(NBLK), dim3(256), args, 0, stream);
}

// Round 14
// 525.508 us; speedup vs baseline: 1.4186x; 1.1276x over previous
//
#include <hip/hip_runtime.h>
#include <cstddef>
#include <cstdint>

// Problem constants (from setup_inputs)
#define AA 512      // atoms
#define KK 256      // atom size
#define TT 16384    // signal length
#define BB 4        // batch
#define PP 128      // pad = K/2
#define LL 16385    // feature map length = T + 2P - K + 1
#define LPAD 16388  // fm row stride, padded to multiple of 4 for float4 stores
#define NC 65      // number of 256-wide chunks covering LL
#define NT2 33      // position tiles of 512 covering LL
#define SDN 260     // s_dn row stride (floats): 16B-aligned, bank offset 4/row

// 4-float-granularity LDS swizzle: bank rotation of 4 per 32-float block.
static __device__ __forceinline__ int swz4(int i){ return i + ((i >> 5) << 2); }

// Packed per-atom max key: (sortable(v) << 32) | ~l  -> max key == (max v, min l).
// 0 is strictly below any real key (min real key ~ 0x00800000_xxxxxxxx).
static __device__ __forceinline__ unsigned long long packkey(float v, int l){
  unsigned int u = __float_as_uint(v);
  unsigned int s = (u & 0x80000000u) ? ~u : (u | 0x80000000u);
  return ((unsigned long long)s << 32) | (unsigned int)(~l);
}
static __device__ __forceinline__ float unpack_v(unsigned long long k){
  unsigned int s = (unsigned int)(k >> 32);
  unsigned int u = (s & 0x80000000u) ? (s & 0x7FFFFFFFu) : ~s;
  return __uint_as_float(u);
}
static __device__ __forceinline__ int unpack_l(unsigned long long k){
  return (int)(~(unsigned int)k);
}

// ---------------- normalize dictionary atoms (+ zero out, zero amk) ----------------
__global__ void k_norm(const float* __restrict__ d, float* __restrict__ dn,
                       float* __restrict__ out, unsigned long long* __restrict__ amk){
  int a = blockIdx.x, t = threadIdx.x;
  if (t < 128) out[a*128 + t] = 0.f;          // 512 blocks x 128 = BB*TT
  if (a == 0){ for (int i = t; i < 2*BB*AA; i += 256) amk[i] = 0ull; }
  float v = d[a*KK + t];
  float s = v*v;
  #pragma unroll
  for (int off = 32; off > 0; off >>= 1) s += __shfl_down(s, off, 64);
  __shared__ float red[4];
  if ((t & 63) == 0) red[t >> 6] = s;
  __syncthreads();
  float tot = red[0] + red[1] + red[2] + red[3];
  dn[a*KK + t] = v / (sqrtf(tot) + 1e-8f);
}

// ---------------- 32-position ring-buffer correlation core ----------------
// acc[j] = sum_{k=0..255} dnrow[k] * s_r[swz4(32*tx + j + k)], j = 0..31.
// K-ascending fmaf chain per acc[j] (bitwise-stable across kernel versions).
__device__ __forceinline__ void corr32(const float* __restrict__ s_r,
                                       const float* __restrict__ dnrow,
                                       int tx, float acc[32]){
  const int base = tx*32;
  float r[32];
  #pragma unroll
  for (int q = 0; q < 8; ++q){
    float4 v = *(const float4*)(s_r + swz4(base + 4*q));
    r[4*q] = v.x; r[4*q+1] = v.y; r[4*q+2] = v.z; r[4*q+3] = v.w;
  }
  #pragma unroll
  for (int j = 0; j < 32; ++j) acc[j] = 0.f;
  for (int kb = 0; kb < 8; ++kb){            // k = kb*32 + kq*4 + kk
    #pragma unroll
    for (int kq = 0; kq < 8; ++kq){
      const int k0 = kb*32 + kq*4;
      const float4 w4 = *(const float4*)(dnrow + k0);                 // 4 weights
      const float4 f4 = *(const float4*)(s_r + swz4(base + k0 + 32)); // 4 refills
      #pragma unroll
      for (int kk = 0; kk < 4; ++kk){
        const float w = (&w4.x)[kk];
        const int km = (kq*4 + kk) & 31;     // k mod 32, compile-time
        #pragma unroll
        for (int j = 0; j < 32; ++j)
          acc[j] = fmaf(w, r[(km + j) & 31], acc[j]);
        r[km] = (&f4.x)[kk];                 // window slides by 1
      }
    }
  }
}

// ---------------- initial feature map + chunk maxima + packed row maxima ----------------
// block: 256 thr = 16 tx (32 positions each) x 16 ty (atoms); tile 16x512
__global__ __launch_bounds__(256) void k_fm_init(const float* __restrict__ x,
                                                 const float* __restrict__ dn,
                                                 float* __restrict__ fm,
                                                 float* __restrict__ cmv,
                                                 int* __restrict__ cml,
                                                 unsigned long long* __restrict__ amk0){
  const int lt = blockIdx.x, at = blockIdx.y, b = blockIdx.z;
  const int l0 = lt*512, a0 = at*16;
  const int tid = threadIdx.x;
  const int tx = tid & 15, ty = tid >> 4;

  __shared__ __align__(16) float s_r[860];      // 768 swizzled floats
  __shared__ __align__(16) float s_dn[16*SDN];  // 16 atoms, stride 260

  for (int i = tid; i < 768; i += 256){
    int t = l0 + i - PP;                        // padded coords -> signal index
    s_r[swz4(i)] = (t >= 0 && t < TT) ? x[b*TT + t] : 0.f;
  }
  for (int i = tid; i < 16*KK; i += 256){
    int aa = i >> 8, k = i & 255;
    s_dn[aa*SDN + k] = dn[(size_t)(a0 + aa)*KK + k];
  }
  __syncthreads();

  float acc[32];
  corr32(s_r, &s_dn[ty*SDN], tx, acc);

  const int base = tx*32;
  const size_t rowoff = ((size_t)b*AA + a0 + ty)*LPAD + l0 + base;
  float best = -1e30f; int bestl = l0 + base;
  if (l0 + 512 <= LL){
    #pragma unroll
    for (int q = 0; q < 8; ++q){
      float4 v4; v4.x = acc[4*q]; v4.y = acc[4*q+1]; v4.z = acc[4*q+2]; v4.w = acc[4*q+3];
      *(float4*)(fm + rowoff + 4*q) = v4;
    }
    #pragma unroll
    for (int j = 0; j < 32; ++j)
      if (acc[j] > best){ best = acc[j]; bestl = l0 + base + j; }
  } else {
    #pragma unroll
    for (int j = 0; j < 32; ++j){
      int l = l0 + base + j;
      if (l < LL){
        fm[rowoff + j] = acc[j];
        if (acc[j] > best){ best = acc[j]; bestl = l; }
      }
    }
  }
  // thread's 32 positions sit in one 256-chunk: chunk = lt*2 + (tx>>3).
  // reduce across the 8 tx lanes of that chunk (within wave, same ty)
  #pragma unroll
  for (int m = 1; m < 8; m <<= 1){
    float ov = __shfl_xor(best, m, 64);
    int   ol = __shfl_xor(bestl, m, 64);
    if (ov > best || (ov == best && ol < bestl)){ best = ov; bestl = ol; }
  }
  int ch = lt*2 + (tx >> 3);
  if ((tx & 7) == 0 && ch < NC){
    size_t ci = ((size_t)b*AA + a0 + ty)*NC + ch;
    cmv[ci] = best; cml[ci] = bestl;
  }
  // combine the two chunk bests -> block-local row best; atomic into packed row max
  {
    float ov = __shfl_xor(best, 8, 64);
    int   ol = __shfl_xor(bestl, 8, 64);
    if (ov > best || (ov == best && ol < bestl)){ best = ov; bestl = ol; }
  }
  if (tx == 0)
    atomicMax(&amk0[(size_t)b*AA + a0 + ty], packkey(best, bestl));
}

// ---------------- fused iteration: select + rec + fm update + chunk/row refresh ----------------
// grid (32, BB); block 256 = 16 tx x 16 ty(atoms).
// amk double-buffered: reads buf[it&1], writes buf[(it+1)&1] (no in-launch race).
__global__ __launch_bounds__(256) void k_it(const float* __restrict__ dn,
                                            float* __restrict__ fm,
                                            float* __restrict__ cmv, int* __restrict__ cml,
                                            unsigned long long* __restrict__ amk,
                                            float* __restrict__ out,
                                            const int* __restrict__ nit, int it){
  const int n = *nit;
  if (it >= n) return;
  const int as = blockIdx.x, b = blockIdx.y, a0 = as*16;
  const int tid = threadIdx.x, tx = tid & 15, ty = tid >> 4;

  __shared__ __align__(16) float s_e[860];     // zero-extended dn[sel_atom]
  __shared__ __align__(16) float s_dn[16*SDN];
  __shared__ float sv[256]; __shared__ int sa[256]; __shared__ int sl[256];

  // ---- select: argmax over this b's 512 packed per-atom maxima (redundant per block)
  {
    const unsigned long long* av = amk + (size_t)(it & 1)*BB*AA + (size_t)b*AA;
    unsigned long long kA = av[tid], kB = av[tid + 256];
    float vA = unpack_v(kA), vB = unpack_v(kB);
    float best = vA; int ba = tid, bl = unpack_l(kA);
    if (vB > vA){ best = vB; ba = tid + 256; bl = unpack_l(kB); }  // strict > keeps low atom
    sv[tid] = best; sa[tid] = ba; sl[tid] = bl;
    __syncthreads();
    for (int s = 128; s > 0; s >>= 1){
      if (tid < s){
        float ov = sv[tid+s]; int oa = sa[tid+s], ol = sl[tid+s];
        bool take = ov > sv[tid] || (ov == sv[tid] && oa < sa[tid]);
        if (take){ sv[tid] = ov; sa[tid] = oa; sl[tid] = ol; }
      }
      __syncthreads();
    }
  }
  const float val = sv[0]; const int c = sa[0], pos = sl[0];

  // ---- reconstruction write (one block per b)
  if (as == 0){
    int t = pos + tid - PP;
    if (t >= 0 && t < TT) out[b*TT + t] += val * dn[(size_t)c*KK + tid];
  }
  if (it == 7 || it + 1 >= n) return;          // last iteration: no update needed

  // ---- stage zero-extended selected atom + this block's 16 atoms
  for (int i = tid; i < 768; i += 256){
    int k = i - 256;
    s_e[swz4(i)] = (k >= 0 && k < KK) ? dn[(size_t)c*KK + k] : 0.f;
  }
  for (int i = tid; i < 16*KK; i += 256){
    int aa = i >> 8, k = i & 255;
    s_dn[aa*SDN + k] = dn[(size_t)(a0 + aa)*KK + k];
  }
  __syncthreads();

  float acc[32];                               // acc[j] = G(a0+ty, c, 32*tx + j - 256)
  corr32(s_e, &s_dn[ty*SDN], tx, acc);

  const size_t rb = ((size_t)b*AA + a0 + ty)*LPAD;
  const int lb = pos - 256 + tx*32;
  #pragma unroll
  for (int j = 0; j < 32; ++j){
    int l = lb + j;
    if (l >= 0 && l < LL) fm[rb + l] -= val * acc[j];
  }
  __syncthreads();   // block's fm updates visible block-wide (rows owned per-block)

  // ---- refresh touched chunks (<=3)
  int lo = pos - 255; if (lo < 0) lo = 0;
  int hi = pos + 255; if (hi > LL-1) hi = LL-1;
  const int c0 = lo >> 8, c1 = hi >> 8;
  for (int ch = c0; ch <= c1; ++ch){
    int lbase = ch*256 + tx*16;
    float best = -1e30f; int bestl = lbase;
    #pragma unroll
    for (int j = 0; j < 16; ++j){
      int l = lbase + j;
      if (l < LL){
        float v = fm[rb + l];
        if (v > best){ best = v; bestl = l; }
      }
    }
    #pragma unroll
    for (int m = 1; m < 16; m <<= 1){
      float ov = __shfl_xor(best, m, 64);
      int   ol = __shfl_xor(bestl, m, 64);
      if (ov > best || (ov == best && ol < bestl)){ best = ov; bestl = ol; }
    }
    if (tx == 0){
      size_t ci = ((size_t)b*AA + a0 + ty)*NC + ch;
      cmv[ci] = best; cml[ci] = bestl;
    }
  }
  __syncthreads();   // fresh cmv visible block-wide

  // ---- recompute this block's 16 per-atom row maxima -> NEXT packed buffer
  const size_t row = (size_t)b*AA + a0 + ty;
  float best = -1e30f; int bestl = 0;
  for (int cc = tx; cc < NC; cc += 16){
    float v = cmv[row*NC + cc]; int l = cml[row*NC + cc];
    if (v > best || (v == best && l < bestl)){ best = v; bestl = l; }
  }
  #pragma unroll
  for (int m = 1; m < 16; m <<= 1){
    float ov = __shfl_xor(best, m, 64);
    int   ol = __shfl_xor(bestl, m, 64);
    if (ov > best || (ov == best && ol < bestl)){ best = ov; bestl = ol; }
  }
  if (tx == 0)
    amk[(size_t)((it + 1) & 1)*BB*AA + row] = packkey(best, bestl);
}

extern "C" void kernel_launch(void* const* d_in, const int* in_sizes, int n_in,
                              void* d_out, int out_size, void* d_ws, size_t ws_size,
                              hipStream_t stream){
  const float* x  = (const float*)d_in[0];
  const float* d  = (const float*)d_in[1];
  const int*  nit = (const int*)d_in[2];
  float* out = (float*)d_out;

  // workspace carve
  float* dn  = (float*)d_ws;                       // AA*KK f32
  float* fm  = dn  + (size_t)AA*KK;                // BB*AA*LPAD f32
  float* cmv = fm  + (size_t)BB*AA*LPAD;           // BB*AA*NC f32
  int*   cml = (int*)(cmv + (size_t)BB*AA*NC);     // BB*AA*NC i32
  unsigned long long* amk =
      (unsigned long long*)(cml + (size_t)BB*AA*NC); // 2*BB*AA u64 (8B-aligned: offset /8 integral)
  size_t need = (size_t)((char*)(amk + (size_t)2*BB*AA) - (char*)d_ws);
  if (ws_size < need) return;  // visible failure instead of OOB corruption

  k_norm<<<AA, KK, 0, stream>>>(d, dn, out, amk);
  k_fm_init<<<dim3(NT2, AA/16, BB), 256, 0, stream>>>(x, dn, fm, cmv, cml, amk);
  for (int it = 0; it < 8; ++it)
    k_it<<<dim3(AA/16, BB), 256, 0, stream>>>(dn, fm, cmv, cml, amk, out, nit, it);
}